// Round 4
// baseline (47.664 us; speedup 1.0000x reference)
//
#include <hip/hip_runtime.h>

#define HID 64
#define NROWS 1036
#define KNOTS 64    // intervals; table has KNOTS+1 rows
#define SPW 4       // samples per wave
#define ROWCHUNKS 5 // table-build row parallelism (208 rows/chunk <= 256 thr)

// Packed per-knot layout (1036 floats):
//   [0..7]       a1 (RANK x COORD, row-major)          -- uniform across lanes
//   [8..263]     b1[h][r] = 8 + 4h + r                 -- per-lane float4
//   [264..519]   a2t[k][r] = 264 + 4k + r (TRANSPOSED) -- per-lane float4
//   [520..775]   b2[h][r] = 520 + 4h + r               -- per-lane float4
//   [776..1031]  a3t[k][r] = 776 + 4k + r (TRANSPOSED) -- per-lane float4
//   [1032..1035] b3[r]                                 -- uniform
#define A1_OFF 0
#define B1_OFF 8
#define A2T_OFF 264
#define B2_OFF 520
#define A3T_OFF 776
#define B3_OFF 1032

__device__ __align__(16) float gTable[(KNOTS + 1) * NROWS];

__device__ inline int pack_idx(int i) {
    if (i >= A2T_OFF && i < B2_OFF) { int o = i - A2T_OFF; return A2T_OFF + ((o & 63) << 2) + (o >> 6); }
    if (i >= A3T_OFF && i < B3_OFF) { int o = i - A3T_OFF; return A3T_OFF + ((o & 63) << 2) + (o >> 6); }
    return i;
}

__global__ void build_table_kernel(const float* __restrict__ Wh1,
                                   const float* __restrict__ Bh1,
                                   const float* __restrict__ Wh2,
                                   const float* __restrict__ Bh2) {
    __shared__ float h[HID];
    const int j = blockIdx.x / ROWCHUNKS;          // 0..KNOTS
    const int chunk = blockIdx.x % ROWCHUNKS;
    const float p = (float)j / (float)KNOTS;
    const int t = threadIdx.x;
    if (t < HID) h[t] = tanhf(fmaf(p, Wh1[t], Bh1[t]));
    __syncthreads();
    const int rows = (NROWS + ROWCHUNKS - 1) / ROWCHUNKS;   // 208
    const int r0 = chunk * rows;
    const int r1 = min(NROWS, r0 + rows);
    for (int i = r0 + t; i < r1; i += blockDim.x) {
        const float4* row = (const float4*)(Wh2 + i * HID);
        float a0 = 0.f, a1 = 0.f, a2 = 0.f, a3 = 0.f;
        #pragma unroll
        for (int q = 0; q < 16; ++q) {
            float4 w = row[q];
            a0 = fmaf(w.x, h[4 * q + 0], a0);
            a1 = fmaf(w.y, h[4 * q + 1], a1);
            a2 = fmaf(w.z, h[4 * q + 2], a2);
            a3 = fmaf(w.w, h[4 * q + 3], a3);
        }
        gTable[j * NROWS + pack_idx(i)] = Bh2[i] + (a0 + a1) + (a2 + a3);
    }
}

// ---- DPP wave64 sum (VALU pipe only). Result lands in lane 63. ----
template <int CTRL>
__device__ inline float dpp_add(float v) {
    int t = __builtin_amdgcn_update_dpp(0, __float_as_int(v), CTRL, 0xf, 0xf, true);
    return v + __int_as_float(t);
}
__device__ inline float wave_sum63(float v) {
    v = dpp_add<0x111>(v);  // row_shr:1
    v = dpp_add<0x112>(v);  // row_shr:2
    v = dpp_add<0x114>(v);  // row_shr:4
    v = dpp_add<0x118>(v);  // row_shr:8
    v = dpp_add<0x142>(v);  // row_bcast15
    v = dpp_add<0x143>(v);  // row_bcast31 -> lane63 has full sum
    return v;
}
__device__ inline float bcast63(float v) {
    return __int_as_float(__builtin_amdgcn_readlane(__float_as_int(v), 63));
}
__device__ inline float rfl_f(float v) {
    return __uint_as_float(__builtin_amdgcn_readfirstlane(__float_as_uint(v)));
}

__device__ inline float tanh_fast(float x) {
    return 1.0f - __fdividef(2.0f, __expf(2.0f * x) + 1.0f);
}

// bf16 pair pack/unpack (RNE)
__device__ inline unsigned bf16bits(float x) {
    unsigned u = __float_as_uint(x);
    return (u + 0x7fffu + ((u >> 16) & 1u)) & 0xffff0000u;
}
__device__ inline unsigned packbf(float a, float b) {
    return (bf16bits(a) >> 16) | bf16bits(b);
}
__device__ inline float bflo(unsigned u) { return __uint_as_float(u << 16); }
__device__ inline float bfhi(unsigned u) { return __uint_as_float(u & 0xffff0000u); }

__device__ inline float4 ld4(const float* p) { return *(const float4*)p; }
__device__ inline float4 lerp4(float4 lo, float4 hi, float f) {
    float4 r;
    r.x = fmaf(f, hi.x - lo.x, lo.x);
    r.y = fmaf(f, hi.y - lo.y, lo.y);
    r.z = fmaf(f, hi.z - lo.z, lo.z);
    r.w = fmaf(f, hi.w - lo.w, lo.w);
    return r;
}

struct Raw { float4 b1a, b1b, a2a, a2b, b2a, b2b, a3a, a3b; };

__device__ inline Raw load_raw(const float* __restrict__ T0,
                               const float* __restrict__ T1, int lane4) {
    Raw r;
    r.b1a = ld4(T0 + B1_OFF  + lane4);
    r.b1b = ld4(T1 + B1_OFF  + lane4);
    r.a2a = ld4(T0 + A2T_OFF + lane4);
    r.a2b = ld4(T1 + A2T_OFF + lane4);
    r.b2a = ld4(T0 + B2_OFF  + lane4);
    r.b2b = ld4(T1 + B2_OFF  + lane4);
    r.a3a = ld4(T0 + A3T_OFF + lane4);
    r.a3b = ld4(T1 + A3T_OFF + lane4);
    return r;
}

__global__ __launch_bounds__(256, 4) void hyper_main(
    const float* __restrict__ coords, const float* __restrict__ param,
    const float* __restrict__ W1, const float* __restrict__ B1,
    const float* __restrict__ W2, const float* __restrict__ B2,
    const float* __restrict__ W3, const float* __restrict__ B3,
    float* __restrict__ out, int n) {
    __shared__ __align__(16) float x1s[4][HID];
    __shared__ __align__(16) float ab3[(KNOTS + 1) * 12];  // [j]{a1[8], b3[4]}

    const int tid = threadIdx.x;
    const int wid = tid >> 6;
    const int lane = tid & 63;
    const int lane4 = 4 * lane;

    // Stage a1/b3 mini-table (65 x 12 floats) into LDS.
    for (int i = tid; i < (KNOTS + 1) * 12; i += 256) {
        const int j = i / 12;
        const int o = i - 12 * j;
        ab3[i] = gTable[j * NROWS + (o < 8 ? A1_OFF + o : B3_OFF + o - 8)];
    }

    // W2 row -> registers as packed bf16 pairs (32 VGPR).
    uint2 w2p[16];
    {
        const float4* wrow = (const float4*)(W2 + lane * HID);
        #pragma unroll
        for (int q = 0; q < 16; ++q) {
            const float4 w = wrow[q];
            w2p[q].x = packbf(w.x, w.y);
            w2p[q].y = packbf(w.z, w.w);
        }
    }

    const float w1a = W1[2 * lane];
    const float w1b = W1[2 * lane + 1];
    const float b1l = B1[lane];
    const float b2l = B2[lane];
    const float w3l = W3[lane];
    const float b3s = B3[0];

    __syncthreads();   // ab3 ready

    const int base = __builtin_amdgcn_readfirstlane(blockIdx.x * (4 * SPW) + wid);

    // Preload all SPW sample scalars (wave-uniform -> force SGPR).
    int ss[SPW], jj[SPW];
    float ffv[SPW], c0a[SPW], c1a[SPW];
    #pragma unroll
    for (int it = 0; it < SPW; ++it) {
        int s = base + 4 * it;
        ss[it] = (s < n) ? s : (n - 1);
        const float p = rfl_f(param[ss[it]]);
        c0a[it] = rfl_f(coords[2 * ss[it]]);
        c1a[it] = rfl_f(coords[2 * ss[it] + 1]);
        float pf = p * (float)KNOTS;
        int j = (int)pf;
        j = max(0, min(KNOTS - 1, j));
        jj[it] = __builtin_amdgcn_readfirstlane(j);
        ffv[it] = rfl_f(pf - (float)j);
    }

    // Pipeline prologue: issue sample 0's per-lane table loads.
    Raw raw = load_raw(gTable + jj[0] * NROWS, gTable + (jj[0] + 1) * NROWS, lane4);

    #pragma unroll
    for (int it = 0; it < SPW; ++it) {
        const float f = ffv[it];
        const float c0 = c0a[it], c1 = c1a[it];

        // Consume raw buffer -> lerped fragments.
        const float4 b1v = lerp4(raw.b1a, raw.b1b, f);
        const float4 a2v = lerp4(raw.a2a, raw.a2b, f);
        const float4 b2v = lerp4(raw.b2a, raw.b2b, f);
        const float4 a3v = lerp4(raw.a3a, raw.a3b, f);

        // Issue next sample's loads NOW — in flight during this compute.
        if (it + 1 < SPW)
            raw = load_raw(gTable + jj[it + 1] * NROWS,
                           gTable + (jj[it + 1] + 1) * NROWS, lane4);

        // Uniform a1/b3 pieces from LDS mini-table (broadcast reads).
        const float* U0 = ab3 + jj[it] * 12;
        const float4 a1lo = lerp4(ld4(U0),     ld4(U0 + 12), f);
        const float4 a1hi = lerp4(ld4(U0 + 4), ld4(U0 + 16), f);
        const float4 b3v  = lerp4(ld4(U0 + 8), ld4(U0 + 20), f);

        // ---- layer 1 (h = lane) ----
        const float t10 = fmaf(c0, a1lo.x, c1 * a1lo.y);
        const float t11 = fmaf(c0, a1lo.z, c1 * a1lo.w);
        const float t12 = fmaf(c0, a1hi.x, c1 * a1hi.y);
        const float t13 = fmaf(c0, a1hi.z, c1 * a1hi.w);
        const float lr1 = t10 * b1v.x + t11 * b1v.y + t12 * b1v.z + t13 * b1v.w;
        const float x1 = tanh_fast(fmaf(c0, w1a, fmaf(c1, w1b, lr1 + b1l)));

        x1s[wid][lane] = x1;   // same-wave write->read; no barrier needed

        // ---- W2 @ x1: packed-bf16 registers x LDS-broadcast float4 ----
        const float4* xv = (const float4*)x1s[wid];
        float ac0 = 0.f, ac1 = 0.f, ac2 = 0.f, ac3 = 0.f;
        #pragma unroll
        for (int q = 0; q < 16; ++q) {
            const float4 xk = xv[q];
            const uint2 w = w2p[q];
            ac0 = fmaf(bflo(w.x), xk.x, ac0);
            ac1 = fmaf(bfhi(w.x), xk.y, ac1);
            ac2 = fmaf(bflo(w.y), xk.z, ac2);
            ac3 = fmaf(bfhi(w.y), xk.w, ac3);
        }
        const float w2dot = (ac0 + ac1) + (ac2 + ac3);

        // ---- low-rank 2: four DPP reductions ----
        const float t20 = bcast63(wave_sum63(x1 * a2v.x));
        const float t21 = bcast63(wave_sum63(x1 * a2v.y));
        const float t22 = bcast63(wave_sum63(x1 * a2v.z));
        const float t23 = bcast63(wave_sum63(x1 * a2v.w));
        const float lr2 = t20 * b2v.x + t21 * b2v.y + t22 * b2v.z + t23 * b2v.w;
        const float x2 = tanh_fast(w2dot + lr2 + b2l);

        // ---- output layer folded into ONE reduction ----
        const float weff = w3l + b3v.x * a3v.x + b3v.y * a3v.y
                               + b3v.z * a3v.z + b3v.w * a3v.w;
        const float osum = wave_sum63(x2 * weff);
        if (lane == 63 && (base + 4 * it) < n) out[ss[it]] = osum + b3s;
    }
}

extern "C" void kernel_launch(void* const* d_in, const int* in_sizes, int n_in,
                              void* d_out, int out_size, void* d_ws, size_t ws_size,
                              hipStream_t stream) {
    const float* coords = (const float*)d_in[0];
    const float* param  = (const float*)d_in[1];
    const float* W1  = (const float*)d_in[2];
    const float* B1  = (const float*)d_in[3];
    const float* W2  = (const float*)d_in[4];
    const float* B2  = (const float*)d_in[5];
    const float* W3  = (const float*)d_in[6];
    const float* B3  = (const float*)d_in[7];
    const float* Wh1 = (const float*)d_in[8];
    const float* Bh1 = (const float*)d_in[9];
    const float* Wh2 = (const float*)d_in[10];
    const float* Bh2 = (const float*)d_in[11];
    float* out = (float*)d_out;
    const int n = out_size;                 // 32768 samples

    build_table_kernel<<<(KNOTS + 1) * ROWCHUNKS, 256, 0, stream>>>(Wh1, Bh1, Wh2, Bh2);

    const int spb = 4 * SPW;                // samples per block (16)
    const int nblocks = (n + spb - 1) / spb;
    hyper_main<<<nblocks, 256, 0, stream>>>(coords, param, W1, B1, W2, B2,
                                            W3, B3, out, n);
}

// Round 5
// 43.602 us; speedup vs baseline: 1.0932x; 1.0932x over previous
//
#include <hip/hip_runtime.h>
#include <hip/hip_fp16.h>

#define HID 64
#define NROWS 1036
#define ROWP 1040            // padded f16 row stride (elements, 2080 B)
#define KNOTS 256            // nearest-neighbor: 257 rows, p_j = j/256
#define NKNOT (KNOTS + 1)
#define SPW 4                // samples per wave
#define ROWCHUNKS 4          // table-build row parallelism

// f16 packed per-knot row (indices in f16 elements):
//   [8..263]    b1[h][r]  = 8 + 4h + r     per-lane uint2 @ byte 16+8L
//   [264..519]  a2t[k][r] = 264 + 4k + r   per-lane uint2 @ byte 528+8L
//   [520..775]  b2[h][r]  = 520 + 4h + r   per-lane uint2 @ byte 1040+8L
//   [776..1031] a3t[k][r] = 776 + 4k + r   per-lane uint2 @ byte 1552+8L
// a1[8] + b3[4] live separately in f32 ab3Table[j*12 + {0..11}].
__device__ __align__(16) _Float16 gTableH[NKNOT * ROWP];
__device__ __align__(16) float ab3Table[NKNOT * 12];

__device__ inline int pack_idx(int i) {
    if (i >= 264 && i < 520)  { int o = i - 264; return 264 + ((o & 63) << 2) + (o >> 6); }
    if (i >= 776 && i < 1032) { int o = i - 776; return 776 + ((o & 63) << 2) + (o >> 6); }
    return i;
}

__global__ void build_table_kernel(const float* __restrict__ Wh1,
                                   const float* __restrict__ Bh1,
                                   const float* __restrict__ Wh2,
                                   const float* __restrict__ Bh2) {
    __shared__ float h[HID];
    const int j = blockIdx.x / ROWCHUNKS;          // 0..KNOTS
    const int chunk = blockIdx.x % ROWCHUNKS;
    const float p = (float)j / (float)KNOTS;
    const int t = threadIdx.x;
    if (t < HID) h[t] = tanhf(fmaf(p, Wh1[t], Bh1[t]));
    __syncthreads();
    const int rows = (NROWS + ROWCHUNKS - 1) / ROWCHUNKS;   // 259
    const int r0 = chunk * rows;
    const int r1 = min(NROWS, r0 + rows);
    for (int i = r0 + t; i < r1; i += blockDim.x) {
        const float4* row = (const float4*)(Wh2 + i * HID);
        float a0 = 0.f, a1 = 0.f, a2 = 0.f, a3 = 0.f;
        #pragma unroll
        for (int q = 0; q < 16; ++q) {
            float4 w = row[q];
            a0 = fmaf(w.x, h[4 * q + 0], a0);
            a1 = fmaf(w.y, h[4 * q + 1], a1);
            a2 = fmaf(w.z, h[4 * q + 2], a2);
            a3 = fmaf(w.w, h[4 * q + 3], a3);
        }
        const float g = Bh2[i] + (a0 + a1) + (a2 + a3);
        gTableH[j * ROWP + pack_idx(i)] = (_Float16)g;
        if (i < 8)          ab3Table[j * 12 + i] = g;
        else if (i >= 1032) ab3Table[j * 12 + 8 + (i - 1032)] = g;
    }
}

// ---- DPP wave64 sum (VALU pipe only). Result lands in lane 63. ----
template <int CTRL>
__device__ inline float dpp_add(float v) {
    int t = __builtin_amdgcn_update_dpp(0, __float_as_int(v), CTRL, 0xf, 0xf, true);
    return v + __int_as_float(t);
}
__device__ inline float wave_sum63(float v) {
    v = dpp_add<0x111>(v);  // row_shr:1
    v = dpp_add<0x112>(v);  // row_shr:2
    v = dpp_add<0x114>(v);  // row_shr:4
    v = dpp_add<0x118>(v);  // row_shr:8
    v = dpp_add<0x142>(v);  // row_bcast15
    v = dpp_add<0x143>(v);  // row_bcast31 -> lane63 has full sum
    return v;
}
__device__ inline float bcast63(float v) {
    return __int_as_float(__builtin_amdgcn_readlane(__float_as_int(v), 63));
}
__device__ inline float rfl_f(float v) {
    return __uint_as_float(__builtin_amdgcn_readfirstlane(__float_as_uint(v)));
}
__device__ inline float tanh_fast(float x) {
    return 1.0f - __fdividef(2.0f, __expf(2.0f * x) + 1.0f);
}

typedef _Float16 half2v __attribute__((ext_vector_type(2)));

__device__ inline float fdot2u(unsigned a, unsigned b, float c) {
#if defined(__has_builtin) && __has_builtin(__builtin_amdgcn_fdot2)
    return __builtin_amdgcn_fdot2(__builtin_bit_cast(half2v, a),
                                  __builtin_bit_cast(half2v, b), c, false);
#else
    half2v av = __builtin_bit_cast(half2v, a);
    half2v bv = __builtin_bit_cast(half2v, b);
    return fmaf((float)av.x, (float)bv.x, fmaf((float)av.y, (float)bv.y, c));
#endif
}
__device__ inline float2 up2(unsigned u) {
    half2v v = __builtin_bit_cast(half2v, u);
    return make_float2((float)v.x, (float)v.y);
}
__device__ inline unsigned packh2(float a, float b) {
    half2v v; v.x = (_Float16)a; v.y = (_Float16)b;
    return __builtin_bit_cast(unsigned, v);
}

struct RawS { uint2 r0, r1, r2, r3; float4 u0, u1, u2; };

__device__ inline RawS load_sample(int j, int lane) {
    RawS s;
    const char* rb = (const char*)gTableH + (size_t)j * (ROWP * 2);
    const int lo = 8 * lane;
    s.r0 = *(const uint2*)(rb + 16   + lo);   // b1
    s.r1 = *(const uint2*)(rb + 528  + lo);   // a2t
    s.r2 = *(const uint2*)(rb + 1040 + lo);   // b2
    s.r3 = *(const uint2*)(rb + 1552 + lo);   // a3t
    const float4* ub = (const float4*)(ab3Table + j * 12);
    s.u0 = ub[0]; s.u1 = ub[1]; s.u2 = ub[2]; // a1[0..7], b3[0..3]
    return s;
}

__global__ __launch_bounds__(256, 4) void hyper_main(
    const float* __restrict__ coords, const float* __restrict__ param,
    const float* __restrict__ W1, const float* __restrict__ B1,
    const float* __restrict__ W2, const float* __restrict__ B2,
    const float* __restrict__ W3, const float* __restrict__ B3,
    float* __restrict__ out, int n) {
    __shared__ __align__(16) _Float16 x1h[4][HID];   // 512 B total LDS

    const int tid = threadIdx.x;
    const int wid = tid >> 6;
    const int lane = tid & 63;

    // W2 row -> 32 packed f16 pairs (32 VGPR), once per wave.
    unsigned w2p[32];
    {
        const float4* wrow = (const float4*)(W2 + lane * HID);
        #pragma unroll
        for (int q = 0; q < 16; ++q) {
            const float4 w = wrow[q];
            w2p[2 * q]     = packh2(w.x, w.y);
            w2p[2 * q + 1] = packh2(w.z, w.w);
        }
    }
    const float w1a = W1[2 * lane], w1b = W1[2 * lane + 1];
    const float b1l = B1[lane], b2l = B2[lane], w3l = W3[lane], b3s = B3[0];

    const int base = __builtin_amdgcn_readfirstlane(blockIdx.x * (4 * SPW) + wid);

    // Wave-uniform sample scalars -> SGPRs.
    int ss[SPW], jj[SPW];
    float c0a[SPW], c1a[SPW];
    #pragma unroll
    for (int it = 0; it < SPW; ++it) {
        int s = base + 4 * it;
        ss[it] = (s < n) ? s : (n - 1);
        const float p = rfl_f(param[ss[it]]);
        c0a[it] = rfl_f(coords[2 * ss[it]]);
        c1a[it] = rfl_f(coords[2 * ss[it] + 1]);
        int j = (int)fmaf(p, (float)KNOTS, 0.5f);   // nearest knot
        j = max(0, min(KNOTS, j));
        jj[it] = __builtin_amdgcn_readfirstlane(j);
    }

    RawS cur = load_sample(jj[0], lane);

    #pragma unroll
    for (int it = 0; it < SPW; ++it) {
        RawS nxt;
        if (it + 1 < SPW) nxt = load_sample(jj[it + 1], lane);  // in flight during compute

        const float c0 = c0a[it], c1 = c1a[it];
        const float2 b1lo = up2(cur.r0.x), b1hi = up2(cur.r0.y);
        const float2 a2lo = up2(cur.r1.x), a2hi = up2(cur.r1.y);
        const float2 b2lo = up2(cur.r2.x), b2hi = up2(cur.r2.y);
        const float2 a3lo = up2(cur.r3.x), a3hi = up2(cur.r3.y);
        const float4 a1l = cur.u0, a1h = cur.u1, b3v = cur.u2;

        // ---- layer 1 (h = lane) ----
        const float t10 = fmaf(c0, a1l.x, c1 * a1l.y);
        const float t11 = fmaf(c0, a1l.z, c1 * a1l.w);
        const float t12 = fmaf(c0, a1h.x, c1 * a1h.y);
        const float t13 = fmaf(c0, a1h.z, c1 * a1h.w);
        const float lr1 = t10 * b1lo.x + t11 * b1lo.y + t12 * b1hi.x + t13 * b1hi.y;
        const float x1 = tanh_fast(fmaf(c0, w1a, fmaf(c1, w1b, lr1 + b1l)));

        x1h[wid][lane] = (_Float16)x1;   // same-wave write->read, no barrier

        // ---- W2 @ x1: 32x v_dot2_f32_f16 against LDS-broadcast f16 pairs ----
        const uint4* xv = (const uint4*)x1h[wid];   // 8 x 16B
        float ac0 = 0.f, ac1 = 0.f, ac2 = 0.f, ac3 = 0.f;
        #pragma unroll
        for (int r = 0; r < 8; ++r) {
            const uint4 x4 = xv[r];
            ac0 = fdot2u(w2p[4 * r + 0], x4.x, ac0);
            ac1 = fdot2u(w2p[4 * r + 1], x4.y, ac1);
            ac2 = fdot2u(w2p[4 * r + 2], x4.z, ac2);
            ac3 = fdot2u(w2p[4 * r + 3], x4.w, ac3);
        }
        const float w2dot = (ac0 + ac1) + (ac2 + ac3);

        // ---- low-rank 2: four interleaved DPP reductions (f32 x1) ----
        const float t20 = bcast63(wave_sum63(x1 * a2lo.x));
        const float t21 = bcast63(wave_sum63(x1 * a2lo.y));
        const float t22 = bcast63(wave_sum63(x1 * a2hi.x));
        const float t23 = bcast63(wave_sum63(x1 * a2hi.y));
        const float lr2 = t20 * b2lo.x + t21 * b2lo.y + t22 * b2hi.x + t23 * b2hi.y;
        const float x2 = tanh_fast(w2dot + lr2 + b2l);

        // ---- output layer folded into ONE reduction ----
        const float weff = w3l + b3v.x * a3lo.x + b3v.y * a3lo.y
                               + b3v.z * a3hi.x + b3v.w * a3hi.y;
        const float osum = wave_sum63(x2 * weff);
        if (lane == 63 && (base + 4 * it) < n) out[ss[it]] = osum + b3s;

        cur = nxt;
    }
}

extern "C" void kernel_launch(void* const* d_in, const int* in_sizes, int n_in,
                              void* d_out, int out_size, void* d_ws, size_t ws_size,
                              hipStream_t stream) {
    const float* coords = (const float*)d_in[0];
    const float* param  = (const float*)d_in[1];
    const float* W1  = (const float*)d_in[2];
    const float* B1  = (const float*)d_in[3];
    const float* W2  = (const float*)d_in[4];
    const float* B2  = (const float*)d_in[5];
    const float* W3  = (const float*)d_in[6];
    const float* B3  = (const float*)d_in[7];
    const float* Wh1 = (const float*)d_in[8];
    const float* Bh1 = (const float*)d_in[9];
    const float* Wh2 = (const float*)d_in[10];
    const float* Bh2 = (const float*)d_in[11];
    float* out = (float*)d_out;
    const int n = out_size;                 // 32768 samples

    build_table_kernel<<<NKNOT * ROWCHUNKS, 256, 0, stream>>>(Wh1, Bh1, Wh2, Bh2);

    const int spb = 4 * SPW;                // 16 samples per block
    const int nblocks = (n + spb - 1) / spb;
    hyper_main<<<nblocks, 256, 0, stream>>>(coords, param, W1, B1, W2, B2,
                                            W3, B3, out, n);
}

// Round 6
// 41.416 us; speedup vs baseline: 1.1509x; 1.0528x over previous
//
#include <hip/hip_runtime.h>
#include <hip/hip_fp16.h>

#define HID 64
#define NROWS 1036
#define KNOTS 256            // nearest-neighbor: 257 knots, p_j = j/256
#define NKNOT (KNOTS + 1)
#define SPW 4                // samples per wave

// Per-knot, per-lane 32B record (8 dwords):
//   q0 = { W1eff[h][0], W1eff[h][1], w3eff[h], pad }           (f32)
//   q1 = { b2[h][0..1], b2[h][2..3], a2[0..1][h], a2[2..3][h] } (f16 pairs)
__device__ __align__(16) unsigned recTab[NKNOT * HID * 8];

typedef _Float16 half2v __attribute__((ext_vector_type(2)));

__device__ inline unsigned packh2(float a, float b) {
    half2v v; v.x = (_Float16)a; v.y = (_Float16)b;
    return __builtin_bit_cast(unsigned, v);
}
__device__ inline float2 up2(unsigned u) {
    half2v v = __builtin_bit_cast(half2v, u);
    return make_float2((float)v.x, (float)v.y);
}
__device__ inline float fdot2u(unsigned a, unsigned b, float c) {
#if defined(__has_builtin) && __has_builtin(__builtin_amdgcn_fdot2)
    return __builtin_amdgcn_fdot2(__builtin_bit_cast(half2v, a),
                                  __builtin_bit_cast(half2v, b), c, false);
#else
    half2v av = __builtin_bit_cast(half2v, a);
    half2v bv = __builtin_bit_cast(half2v, b);
    return fmaf((float)av.x, (float)bv.x, fmaf((float)av.y, (float)bv.y, c));
#endif
}

// Build: one block per knot. Stage h=tanh(p*Wh1+Bh1), compute all 1036 g
// values into LDS, then fold the low-rank factors into effective weights.
__global__ __launch_bounds__(256) void build_eff_kernel(
    const float* __restrict__ Wh1, const float* __restrict__ Bh1,
    const float* __restrict__ Wh2, const float* __restrict__ Bh2,
    const float* __restrict__ W1,  const float* __restrict__ W3) {
    __shared__ float h[HID];
    __shared__ float g[NROWS];
    const int j = blockIdx.x;                      // 0..256
    const float p = (float)j / (float)KNOTS;
    const int t = threadIdx.x;
    if (t < HID) h[t] = tanhf(fmaf(p, Wh1[t], Bh1[t]));
    __syncthreads();
    for (int i = t; i < NROWS; i += 256) {
        const float4* row = (const float4*)(Wh2 + i * HID);
        float a0 = 0.f, a1 = 0.f, a2 = 0.f, a3 = 0.f;
        #pragma unroll
        for (int q = 0; q < 16; ++q) {
            float4 w = row[q];
            a0 = fmaf(w.x, h[4 * q + 0], a0);
            a1 = fmaf(w.y, h[4 * q + 1], a1);
            a2 = fmaf(w.z, h[4 * q + 2], a2);
            a3 = fmaf(w.w, h[4 * q + 3], a3);
        }
        g[i] = Bh2[i] + (a0 + a1) + (a2 + a3);
    }
    __syncthreads();
    if (t < HID) {
        // g layout: a1[r][c]=g[2r+c], b1[h][r]=g[8+4h+r], a2[r][k]=g[264+64r+k],
        //           b2[h][r]=g[520+4h+r], a3[r][k]=g[776+64r+k], b3[r]=g[1032+r]
        const float* b1 = g + 8 + 4 * t;
        float w1e0 = W1[2 * t], w1e1 = W1[2 * t + 1];
        #pragma unroll
        for (int r = 0; r < 4; ++r) {
            w1e0 = fmaf(b1[r], g[2 * r],     w1e0);
            w1e1 = fmaf(b1[r], g[2 * r + 1], w1e1);
        }
        float w3e = W3[t];
        #pragma unroll
        for (int r = 0; r < 4; ++r)
            w3e = fmaf(g[1032 + r], g[776 + 64 * r + t], w3e);

        uint4 q0, q1;
        q0.x = __float_as_uint(w1e0);
        q0.y = __float_as_uint(w1e1);
        q0.z = __float_as_uint(w3e);
        q0.w = 0u;
        const float* b2 = g + 520 + 4 * t;
        q1.x = packh2(b2[0], b2[1]);
        q1.y = packh2(b2[2], b2[3]);
        q1.z = packh2(g[264 + t], g[264 + 64 + t]);        // a2[0][h], a2[1][h]
        q1.w = packh2(g[264 + 128 + t], g[264 + 192 + t]); // a2[2][h], a2[3][h]
        uint4* dst = (uint4*)(recTab + (j * HID + t) * 8);
        dst[0] = q0;
        dst[1] = q1;
    }
}

// ---- DPP wave64 sum (VALU pipe only). Result lands in lane 63. ----
template <int CTRL>
__device__ inline float dpp_add(float v) {
    int t = __builtin_amdgcn_update_dpp(0, __float_as_int(v), CTRL, 0xf, 0xf, true);
    return v + __int_as_float(t);
}
__device__ inline float wave_sum63(float v) {
    v = dpp_add<0x111>(v);  // row_shr:1
    v = dpp_add<0x112>(v);  // row_shr:2
    v = dpp_add<0x114>(v);  // row_shr:4
    v = dpp_add<0x118>(v);  // row_shr:8
    v = dpp_add<0x142>(v);  // row_bcast15
    v = dpp_add<0x143>(v);  // row_bcast31 -> lane63 has full sum
    return v;
}
__device__ inline float bcast63(float v) {
    return __int_as_float(__builtin_amdgcn_readlane(__float_as_int(v), 63));
}
__device__ inline float rfl_f(float v) {
    return __uint_as_float(__builtin_amdgcn_readfirstlane(__float_as_uint(v)));
}
__device__ inline float tanh_fast(float x) {
    return 1.0f - __fdividef(2.0f, __expf(2.0f * x) + 1.0f);
}

__global__ __launch_bounds__(256, 4) void hyper_main(
    const float* __restrict__ coords, const float* __restrict__ param,
    const float* __restrict__ B1, const float* __restrict__ W2,
    const float* __restrict__ B2, const float* __restrict__ B3,
    float* __restrict__ out, int n) {
    __shared__ __align__(16) _Float16 x1h[4][HID];   // 512 B

    const int tid = threadIdx.x;
    const int wid = tid >> 6;
    const int lane = tid & 63;

    // W2 row -> 32 packed f16 pairs (32 VGPR), once per wave.
    unsigned w2p[32];
    {
        const float4* wrow = (const float4*)(W2 + lane * HID);
        #pragma unroll
        for (int q = 0; q < 16; ++q) {
            const float4 w = wrow[q];
            w2p[2 * q]     = packh2(w.x, w.y);
            w2p[2 * q + 1] = packh2(w.z, w.w);
        }
    }
    const float b1l = B1[lane], b2l = B2[lane], b3s = B3[0];

    const int base = __builtin_amdgcn_readfirstlane(blockIdx.x * (4 * SPW) + wid);

    // Wave-uniform sample scalars -> SGPRs, then ALL record loads up front.
    int ss[SPW];
    float c0a[SPW], c1a[SPW];
    uint4 qa0[SPW], qa1[SPW];
    #pragma unroll
    for (int it = 0; it < SPW; ++it) {
        int s = base + 4 * it;
        ss[it] = (s < n) ? s : (n - 1);
        const float p = rfl_f(param[ss[it]]);
        c0a[it] = rfl_f(coords[2 * ss[it]]);
        c1a[it] = rfl_f(coords[2 * ss[it] + 1]);
        int j = (int)fmaf(p, (float)KNOTS, 0.5f);   // nearest knot
        j = max(0, min(KNOTS, j));
        const int jb = __builtin_amdgcn_readfirstlane(j);
        const uint4* rec = (const uint4*)(recTab + (jb * HID + lane) * 8);
        qa0[it] = rec[0];    // independent loads, all in flight together
        qa1[it] = rec[1];
    }

    #pragma unroll
    for (int it = 0; it < SPW; ++it) {
        const float c0 = c0a[it], c1 = c1a[it];
        const uint4 q0 = qa0[it], q1 = qa1[it];

        // ---- layer 1: W1eff folded, 2 fma + tanh ----
        const float x1 = tanh_fast(fmaf(c0, __uint_as_float(q0.x),
                                   fmaf(c1, __uint_as_float(q0.y), b1l)));
        x1h[wid][lane] = (_Float16)x1;   // same-wave write->read, no barrier

        // ---- W2 @ x1: 32x v_dot2_f32_f16 against LDS-broadcast pairs ----
        const uint4* xv = (const uint4*)x1h[wid];
        float ac0 = 0.f, ac1 = 0.f, ac2 = 0.f, ac3 = 0.f;
        #pragma unroll
        for (int r = 0; r < 8; ++r) {
            const uint4 x4 = xv[r];
            ac0 = fdot2u(w2p[4 * r + 0], x4.x, ac0);
            ac1 = fdot2u(w2p[4 * r + 1], x4.y, ac1);
            ac2 = fdot2u(w2p[4 * r + 2], x4.z, ac2);
            ac3 = fdot2u(w2p[4 * r + 3], x4.w, ac3);
        }
        const float w2dot = (ac0 + ac1) + (ac2 + ac3);

        // ---- low-rank 2: four interleaved DPP reductions ----
        const float2 a2lo = up2(q1.z), a2hi = up2(q1.w);
        const float2 b2lo = up2(q1.x), b2hi = up2(q1.y);
        const float t20 = bcast63(wave_sum63(x1 * a2lo.x));
        const float t21 = bcast63(wave_sum63(x1 * a2lo.y));
        const float t22 = bcast63(wave_sum63(x1 * a2hi.x));
        const float t23 = bcast63(wave_sum63(x1 * a2hi.y));
        const float lr2 = t20 * b2lo.x + t21 * b2lo.y + t22 * b2hi.x + t23 * b2hi.y;
        const float x2 = tanh_fast(w2dot + lr2 + b2l);

        // ---- output: w3eff folded -> single reduction ----
        const float osum = wave_sum63(x2 * __uint_as_float(q0.z));
        if (lane == 63 && (base + 4 * it) < n) out[ss[it]] = osum + b3s;
    }
}

extern "C" void kernel_launch(void* const* d_in, const int* in_sizes, int n_in,
                              void* d_out, int out_size, void* d_ws, size_t ws_size,
                              hipStream_t stream) {
    const float* coords = (const float*)d_in[0];
    const float* param  = (const float*)d_in[1];
    const float* W1  = (const float*)d_in[2];
    const float* B1  = (const float*)d_in[3];
    const float* W2  = (const float*)d_in[4];
    const float* B2  = (const float*)d_in[5];
    const float* W3  = (const float*)d_in[6];
    const float* B3  = (const float*)d_in[7];
    const float* Wh1 = (const float*)d_in[8];
    const float* Bh1 = (const float*)d_in[9];
    const float* Wh2 = (const float*)d_in[10];
    const float* Bh2 = (const float*)d_in[11];
    float* out = (float*)d_out;
    const int n = out_size;                 // 32768 samples

    build_eff_kernel<<<NKNOT, 256, 0, stream>>>(Wh1, Bh1, Wh2, Bh2, W1, W3);

    const int spb = 4 * SPW;                // 16 samples per block
    const int nblocks = (n + spb - 1) / spb;
    hyper_main<<<nblocks, 256, 0, stream>>>(coords, param, B1, W2, B2, B3, out, n);
}

// Round 7
// 31.129 us; speedup vs baseline: 1.5312x; 1.3304x over previous
//
#include <hip/hip_runtime.h>

#define HID 64
#define NROWS 1036
#define KNOTS 256            // nearest-neighbor: 257 knots, p_j = j/256
#define NKNOT (KNOTS + 1)

typedef _Float16 half2v __attribute__((ext_vector_type(2)));
typedef _Float16 half8  __attribute__((ext_vector_type(8)));
typedef float    f32x4  __attribute__((ext_vector_type(4)));

// Tables built per launch (deterministic):
__device__ __align__(16) float2   w1T[NKNOT * 64];      // {w1eff0,w1eff1} per h (f32)
__device__ __align__(16) unsigned a2T[NKNOT * 4 * 32];  // [j][r][hpair] f16x2
__device__ __align__(16) uint2    b2T[NKNOT * 64];      // {b2 r01, b2 r23} per h (f16x2)
__device__ __align__(16) float    w3T[NKNOT * 64];      // w3eff per h (f32)
__device__ __align__(16) uint4    w2F[8 * 64];          // W2 A-frags [kb*4+hb][lane], f16x8

__device__ inline unsigned packh2(float a, float b) {
    half2v v; v.x = (_Float16)a; v.y = (_Float16)b;
    return __builtin_bit_cast(unsigned, v);
}
__device__ inline float fdot2u(unsigned a, unsigned b, float c) {
#if defined(__has_builtin) && __has_builtin(__builtin_amdgcn_fdot2)
    return __builtin_amdgcn_fdot2(__builtin_bit_cast(half2v, a),
                                  __builtin_bit_cast(half2v, b), c, false);
#else
    half2v av = __builtin_bit_cast(half2v, a);
    half2v bv = __builtin_bit_cast(half2v, b);
    return fmaf((float)av.x, (float)bv.x, fmaf((float)av.y, (float)bv.y, c));
#endif
}
__device__ inline float tanh_fast(float x) {
    return 1.0f - __fdividef(2.0f, __expf(2.0f * x) + 1.0f);
}

// Build: one block per knot. g[1036] in LDS, then fold into effective tables.
// Block j==0 additionally packs the W2 MFMA A-fragments.
__global__ __launch_bounds__(256) void build_eff_kernel(
    const float* __restrict__ Wh1, const float* __restrict__ Bh1,
    const float* __restrict__ Wh2, const float* __restrict__ Bh2,
    const float* __restrict__ W1,  const float* __restrict__ W3,
    const float* __restrict__ W2) {
    __shared__ float h[HID];
    __shared__ float g[NROWS];
    const int j = blockIdx.x;                      // 0..256
    const float p = (float)j / (float)KNOTS;
    const int t = threadIdx.x;
    if (t < HID) h[t] = tanhf(fmaf(p, Wh1[t], Bh1[t]));
    __syncthreads();
    for (int i = t; i < NROWS; i += 256) {
        const float4* row = (const float4*)(Wh2 + i * HID);
        float a0 = 0.f, a1 = 0.f, a2 = 0.f, a3 = 0.f;
        #pragma unroll
        for (int q = 0; q < 16; ++q) {
            float4 w = row[q];
            a0 = fmaf(w.x, h[4 * q + 0], a0);
            a1 = fmaf(w.y, h[4 * q + 1], a1);
            a2 = fmaf(w.z, h[4 * q + 2], a2);
            a3 = fmaf(w.w, h[4 * q + 3], a3);
        }
        g[i] = Bh2[i] + (a0 + a1) + (a2 + a3);
    }
    __syncthreads();
    // g layout: a1[r][c]=g[2r+c], b1[h][r]=g[8+4h+r], a2[r][k]=g[264+64r+k],
    //           b2[h][r]=g[520+4h+r], a3[r][k]=g[776+64r+k], b3[r]=g[1032+r]
    if (t < HID) {
        const int hh = t;
        const float* b1 = g + 8 + 4 * hh;
        float e0 = W1[2 * hh], e1 = W1[2 * hh + 1];
        #pragma unroll
        for (int r = 0; r < 4; ++r) {
            e0 = fmaf(b1[r], g[2 * r],     e0);
            e1 = fmaf(b1[r], g[2 * r + 1], e1);
        }
        w1T[j * 64 + hh] = make_float2(e0, e1);
        float w3e = W3[hh];
        #pragma unroll
        for (int r = 0; r < 4; ++r)
            w3e = fmaf(g[1032 + r], g[776 + 64 * r + hh], w3e);
        w3T[j * 64 + hh] = w3e;
        b2T[j * 64 + hh] = make_uint2(packh2(g[520 + 4 * hh],     g[520 + 4 * hh + 1]),
                                      packh2(g[520 + 4 * hh + 2], g[520 + 4 * hh + 3]));
    }
    if (t < 128) {
        const int r = t >> 5, pp = t & 31;
        a2T[j * 128 + t] = packh2(g[264 + 64 * r + 2 * pp], g[264 + 64 * r + 2 * pp + 1]);
    }
    if (j == 0) {
        for (int q = t; q < 512; q += 256) {
            const int f = q >> 6, l = q & 63;
            const int kb = f >> 2, hb = f & 3;
            const int m = l & 15, k0 = (l >> 4) * 8;
            const float* src = W2 + (hb * 16 + m) * HID + kb * 32 + k0;
            half8 v;
            #pragma unroll
            for (int i = 0; i < 8; ++i) v[i] = (_Float16)src[i];
            w2F[q] = __builtin_bit_cast(uint4, v);
        }
    }
}

// Main: 1 wave = 16 samples. lane: sl=lane&15 (sample), grp=lane>>4 (k/h group).
__global__ __launch_bounds__(256) void hyper_main(
    const float* __restrict__ coords, const float* __restrict__ param,
    const float* __restrict__ B1, const float* __restrict__ B2,
    const float* __restrict__ B3, float* __restrict__ out, int n) {
    const int tid = threadIdx.x;
    const int wid = tid >> 6;
    const int l = tid & 63;
    const int grp = l >> 4;
    const int sl = l & 15;

    const int s0 = blockIdx.x * 64 + wid * 16;
    int s = s0 + sl;
    if (s >= n) s = n - 1;

    const float p = param[s];
    const float2 c = ((const float2*)coords)[s];
    int j = (int)fmaf(p, (float)KNOTS, 0.5f);
    j = max(0, min(KNOTS, j));

    const int k1 = grp * 8;          // this lane's first k-run (h = k1..k1+7)
    const int k2 = 32 + grp * 8;     // second k-run

    // ---- issue loads ----
    const float4* w1q1 = (const float4*)(w1T + j * 64 + k1);   // 8x float2
    const float4* w1q2 = (const float4*)(w1T + j * 64 + k2);
    const float4 wA0 = w1q1[0], wA1 = w1q1[1], wA2 = w1q1[2], wA3 = w1q1[3];
    const float4 wB0 = w1q2[0], wB1 = w1q2[1], wB2 = w1q2[2], wB3 = w1q2[3];
    const float4 bA0 = ((const float4*)(B1 + k1))[0], bA1 = ((const float4*)(B1 + k1))[1];
    const float4 bB0 = ((const float4*)(B1 + k2))[0], bB1 = ((const float4*)(B1 + k2))[1];

    const uint4* a2p = (const uint4*)(a2T + j * 128);
    uint4 a2r1[4], a2r2[4];
    #pragma unroll
    for (int r = 0; r < 4; ++r) {
        a2r1[r] = a2p[r * 8 + grp];
        a2r2[r] = a2p[r * 8 + 4 + grp];
    }
    uint4 af[8];
    #pragma unroll
    for (int f = 0; f < 8; ++f) af[f] = w2F[f * 64 + l];

    // ---- x1 for this lane's 16 k-values ----
    float x1a[8], x1b[8];
    x1a[0] = tanh_fast(fmaf(c.x, wA0.x, fmaf(c.y, wA0.y, bA0.x)));
    x1a[1] = tanh_fast(fmaf(c.x, wA0.z, fmaf(c.y, wA0.w, bA0.y)));
    x1a[2] = tanh_fast(fmaf(c.x, wA1.x, fmaf(c.y, wA1.y, bA0.z)));
    x1a[3] = tanh_fast(fmaf(c.x, wA1.z, fmaf(c.y, wA1.w, bA0.w)));
    x1a[4] = tanh_fast(fmaf(c.x, wA2.x, fmaf(c.y, wA2.y, bA1.x)));
    x1a[5] = tanh_fast(fmaf(c.x, wA2.z, fmaf(c.y, wA2.w, bA1.y)));
    x1a[6] = tanh_fast(fmaf(c.x, wA3.x, fmaf(c.y, wA3.y, bA1.z)));
    x1a[7] = tanh_fast(fmaf(c.x, wA3.z, fmaf(c.y, wA3.w, bA1.w)));
    x1b[0] = tanh_fast(fmaf(c.x, wB0.x, fmaf(c.y, wB0.y, bB0.x)));
    x1b[1] = tanh_fast(fmaf(c.x, wB0.z, fmaf(c.y, wB0.w, bB0.y)));
    x1b[2] = tanh_fast(fmaf(c.x, wB1.x, fmaf(c.y, wB1.y, bB0.z)));
    x1b[3] = tanh_fast(fmaf(c.x, wB1.z, fmaf(c.y, wB1.w, bB0.w)));
    x1b[4] = tanh_fast(fmaf(c.x, wB2.x, fmaf(c.y, wB2.y, bB1.x)));
    x1b[5] = tanh_fast(fmaf(c.x, wB2.z, fmaf(c.y, wB2.w, bB1.y)));
    x1b[6] = tanh_fast(fmaf(c.x, wB3.x, fmaf(c.y, wB3.y, bB1.z)));
    x1b[7] = tanh_fast(fmaf(c.x, wB3.z, fmaf(c.y, wB3.w, bB1.w)));

    uint4 x1p1, x1p2;
    x1p1.x = packh2(x1a[0], x1a[1]); x1p1.y = packh2(x1a[2], x1a[3]);
    x1p1.z = packh2(x1a[4], x1a[5]); x1p1.w = packh2(x1a[6], x1a[7]);
    x1p2.x = packh2(x1b[0], x1b[1]); x1p2.y = packh2(x1b[2], x1b[3]);
    x1p2.z = packh2(x1b[4], x1b[5]); x1p2.w = packh2(x1b[6], x1b[7]);
    const half8 xb1 = __builtin_bit_cast(half8, x1p1);
    const half8 xb2 = __builtin_bit_cast(half8, x1p2);

    // ---- W2 @ X1 : 8 MFMAs, D[h=hb*16+4*grp+reg][s=sl] ----
    f32x4 acc[4];
    #pragma unroll
    for (int hb = 0; hb < 4; ++hb) {
        acc[hb] = __builtin_amdgcn_mfma_f32_16x16x32_f16(
            __builtin_bit_cast(half8, af[hb]), xb1, (f32x4){0.f, 0.f, 0.f, 0.f}, 0, 0, 0);
        acc[hb] = __builtin_amdgcn_mfma_f32_16x16x32_f16(
            __builtin_bit_cast(half8, af[4 + hb]), xb2, acc[hb], 0, 0, 0);
    }

    // ---- t2[r] = sum_h a2[r][h] x1[h]  (per-lane partial + 2 shuffles) ----
    float t2[4];
    #pragma unroll
    for (int r = 0; r < 4; ++r) {
        float v = 0.f;
        v = fdot2u(a2r1[r].x, x1p1.x, v); v = fdot2u(a2r1[r].y, x1p1.y, v);
        v = fdot2u(a2r1[r].z, x1p1.z, v); v = fdot2u(a2r1[r].w, x1p1.w, v);
        v = fdot2u(a2r2[r].x, x1p2.x, v); v = fdot2u(a2r2[r].y, x1p2.y, v);
        v = fdot2u(a2r2[r].z, x1p2.z, v); v = fdot2u(a2r2[r].w, x1p2.w, v);
        v += __shfl_xor(v, 16);
        v += __shfl_xor(v, 32);
        t2[r] = v;
    }
    const unsigned tp01 = packh2(t2[0], t2[1]);
    const unsigned tp23 = packh2(t2[2], t2[3]);

    // ---- x2 = tanh(acc + b2·t2 + B2), out-partial = sum w3eff·x2 ----
    float osum = 0.f;
    #pragma unroll
    for (int hb = 0; hb < 4; ++hb) {
        const int hbase = hb * 16 + 4 * grp;
        const uint4* bq = (const uint4*)(b2T + j * 64 + hbase);
        const uint4 bA = bq[0], bB = bq[1];
        const float4 w3v = *(const float4*)(w3T + j * 64 + hbase);
        const float4 b2v = *(const float4*)(B2 + hbase);
        const float x20 = tanh_fast(acc[hb][0] + fdot2u(bA.x, tp01, fdot2u(bA.y, tp23, b2v.x)));
        const float x21 = tanh_fast(acc[hb][1] + fdot2u(bA.z, tp01, fdot2u(bA.w, tp23, b2v.y)));
        const float x22 = tanh_fast(acc[hb][2] + fdot2u(bB.x, tp01, fdot2u(bB.y, tp23, b2v.z)));
        const float x23 = tanh_fast(acc[hb][3] + fdot2u(bB.z, tp01, fdot2u(bB.w, tp23, b2v.w)));
        osum = fmaf(w3v.x, x20, fmaf(w3v.y, x21, fmaf(w3v.z, x22, fmaf(w3v.w, x23, osum))));
    }
    osum += __shfl_xor(osum, 16);
    osum += __shfl_xor(osum, 32);

    if (grp == 0 && (s0 + sl) < n) out[s0 + sl] = osum + B3[0];
}

extern "C" void kernel_launch(void* const* d_in, const int* in_sizes, int n_in,
                              void* d_out, int out_size, void* d_ws, size_t ws_size,
                              hipStream_t stream) {
    const float* coords = (const float*)d_in[0];
    const float* param  = (const float*)d_in[1];
    const float* W1  = (const float*)d_in[2];
    const float* B1  = (const float*)d_in[3];
    const float* W2  = (const float*)d_in[4];
    const float* B2  = (const float*)d_in[5];
    const float* W3  = (const float*)d_in[6];
    const float* B3  = (const float*)d_in[7];
    const float* Wh1 = (const float*)d_in[8];
    const float* Bh1 = (const float*)d_in[9];
    const float* Wh2 = (const float*)d_in[10];
    const float* Bh2 = (const float*)d_in[11];
    float* out = (float*)d_out;
    const int n = out_size;                 // 32768 samples

    build_eff_kernel<<<NKNOT, 256, 0, stream>>>(Wh1, Bh1, Wh2, Bh2, W1, W3, W2);

    const int nblocks = (n + 63) / 64;      // 64 samples per block (4 waves x 16)
    hyper_main<<<nblocks, 256, 0, stream>>>(coords, param, B1, B2, B3, out, n);
}